// Round 7
// baseline (13408.675 us; speedup 1.0000x reference)
//
#include <hip/hip_runtime.h>
#include <math.h>

// Problem constants
#define S_LEN 256
#define BATCH 64
#define WLEN  16
#define EC    64
#define HC    128
#define HWID  512
#define TT    32
#define DD    557
#define DDP   576    // padded K for MFMA (mult of 32)
#define NSEQ  16384
#define NSB   16384
#define GC    512    // 4*HC
#define GW    2048   // 4*HWID
#define SCHUNK 16
#define CROWS (SCHUNK*BATCH)   // 1024

typedef unsigned short u16;
typedef __attribute__((ext_vector_type(8))) short bf16x8;
typedef __attribute__((ext_vector_type(4))) float f32x4;

__device__ __forceinline__ float sigf(float x){ return 1.f/(1.f+__expf(-x)); }

// split fp32 -> (hi, lo) bf16 by bit truncation; v ~= hi + lo with ~16 mantissa bits
__device__ __forceinline__ void split2(float v, u16& h, u16& l){
    unsigned int u = __float_as_uint(v);
    h = (u16)(u >> 16);
    float r = v - __uint_as_float(u & 0xffff0000u);
    l = (u16)(__float_as_uint(r) >> 16);
}

// =================== fp32 GEMM (kept for ff2, small N) ================================
#define BM 128
#define BN 128
#define BK 16
__global__ __launch_bounds__(256, 2)
void gemm128(const float* __restrict__ A, int lda,
             const float* __restrict__ Bm, int ldb,
             float* __restrict__ C, int ldc,
             int M, int N, int K,
             const float* __restrict__ bias, int act)
{
    __shared__ float As[BK][BM+4];
    __shared__ float Bs[BK][BN+4];
    const int tid = threadIdx.x;
    const int m0 = blockIdx.x * BM;
    const int n0 = blockIdx.y * BN;
    const int tr = tid >> 4;
    const int tc = tid & 15;
    float acc[8][8];
    #pragma unroll
    for (int i=0;i<8;i++)
        #pragma unroll
        for(int j=0;j<8;j++) acc[i][j]=0.f;

    for (int k0 = 0; k0 < K; k0 += BK) {
        #pragma unroll
        for (int i=0;i<2;i++){
            int e = i*256 + tid;
            int m = e >> 2, kq = e & 3;
            int gm = m0 + m;
            float4 v = make_float4(0.f,0.f,0.f,0.f);
            if (gm < M) v = *(const float4*)&A[(size_t)gm*lda + k0 + kq*4];
            As[kq*4+0][m]=v.x; As[kq*4+1][m]=v.y; As[kq*4+2][m]=v.z; As[kq*4+3][m]=v.w;
        }
        #pragma unroll
        for (int i=0;i<2;i++){
            int e = i*256 + tid;
            int n = e >> 2, kq = e & 3;
            int gn = n0 + n;
            float4 v = make_float4(0.f,0.f,0.f,0.f);
            if (gn < N) v = *(const float4*)&Bm[(size_t)gn*ldb + k0 + kq*4];
            Bs[kq*4+0][n]=v.x; Bs[kq*4+1][n]=v.y; Bs[kq*4+2][n]=v.z; Bs[kq*4+3][n]=v.w;
        }
        __syncthreads();
        #pragma unroll
        for (int k = 0; k < BK; k++) {
            float4 a0 = *(float4*)&As[k][tr*8];
            float4 a1 = *(float4*)&As[k][tr*8+4];
            float4 b0 = *(float4*)&Bs[k][tc*8];
            float4 b1 = *(float4*)&Bs[k][tc*8+4];
            float av[8] = {a0.x,a0.y,a0.z,a0.w,a1.x,a1.y,a1.z,a1.w};
            float bv[8] = {b0.x,b0.y,b0.z,b0.w,b1.x,b1.y,b1.z,b1.w};
            #pragma unroll
            for (int i=0;i<8;i++)
                #pragma unroll
                for (int j=0;j<8;j++)
                    acc[i][j] += av[i]*bv[j];
        }
        __syncthreads();
    }
    #pragma unroll
    for (int i=0;i<8;i++){
        int m = m0 + tr*8 + i;
        if (m >= M) continue;
        #pragma unroll
        for (int j=0;j<8;j++){
            int n = n0 + tc*8 + j;
            if (n >= N) continue;
            float v = acc[i][j];
            if (bias) v += bias[n];
            if (act==1) v = tanhf(v);
            C[(size_t)m*ldc + n] = v;
        }
    }
}

// ============ MFMA split-bf16 GEMM: C = act(A(MxK)*B(NxK)^T + bias) ===================
__global__ __launch_bounds__(256, 2)
void gemm_mfma(const u16* __restrict__ Ah, const u16* __restrict__ Al, int lda,
               const u16* __restrict__ Bh, const u16* __restrict__ Bl, int ldb,
               float* __restrict__ C, int ldc, int K,
               const float* __restrict__ bias, int act)
{
    __shared__ u16 AsH[128*40], AsL[128*40], BsH[128*40], BsL[128*40];
    const int tid  = threadIdx.x;
    const int lane = tid & 63, wv = tid >> 6;
    const int m0 = blockIdx.x * 128, n0 = blockIdx.y * 128;
    const int wm = (wv >> 1) * 64, wn = (wv & 1) * 64;
    const int quad = lane >> 4, l15 = lane & 15;
    const int sr = tid >> 1;            // staging row 0..127
    const int sh = (tid & 1) * 16;      // staging k-half: u16 offset 0 or 16

    f32x4 acc[4][4];
    #pragma unroll
    for (int i=0;i<4;i++)
        #pragma unroll
        for (int j=0;j<4;j++){ f32x4 z = {0.f,0.f,0.f,0.f}; acc[i][j] = z; }

    for (int kc = 0; kc < K; kc += 32){
        const size_t ra = (size_t)(m0+sr)*lda + kc + sh;
        const size_t rb = (size_t)(n0+sr)*ldb + kc + sh;
        uint4 a0 = *(const uint4*)&Ah[ra];
        uint4 a1 = *(const uint4*)&Ah[ra + 8];
        uint4 l0 = *(const uint4*)&Al[ra];
        uint4 l1 = *(const uint4*)&Al[ra + 8];
        uint4 b0 = *(const uint4*)&Bh[rb];
        uint4 b1 = *(const uint4*)&Bh[rb + 8];
        uint4 c0 = *(const uint4*)&Bl[rb];
        uint4 c1 = *(const uint4*)&Bl[rb + 8];
        *(uint4*)&AsH[sr*40 + sh]     = a0;
        *(uint4*)&AsH[sr*40 + sh + 8] = a1;
        *(uint4*)&AsL[sr*40 + sh]     = l0;
        *(uint4*)&AsL[sr*40 + sh + 8] = l1;
        *(uint4*)&BsH[sr*40 + sh]     = b0;
        *(uint4*)&BsH[sr*40 + sh + 8] = b1;
        *(uint4*)&BsL[sr*40 + sh]     = c0;
        *(uint4*)&BsL[sr*40 + sh + 8] = c1;
        __syncthreads();

        bf16x8 afh[4], afl[4], bfh[4], bfl[4];
        #pragma unroll
        for (int mt=0; mt<4; mt++){
            int r = wm + mt*16 + l15;
            afh[mt] = *(const bf16x8*)&AsH[r*40 + quad*8];
            afl[mt] = *(const bf16x8*)&AsL[r*40 + quad*8];
        }
        #pragma unroll
        for (int nt=0; nt<4; nt++){
            int r = wn + nt*16 + l15;
            bfh[nt] = *(const bf16x8*)&BsH[r*40 + quad*8];
            bfl[nt] = *(const bf16x8*)&BsL[r*40 + quad*8];
        }
        #pragma unroll
        for (int mt=0; mt<4; mt++)
            #pragma unroll
            for (int nt=0; nt<4; nt++){
                acc[mt][nt] = __builtin_amdgcn_mfma_f32_16x16x32_bf16(afh[mt], bfh[nt], acc[mt][nt], 0,0,0);
                acc[mt][nt] = __builtin_amdgcn_mfma_f32_16x16x32_bf16(afh[mt], bfl[nt], acc[mt][nt], 0,0,0);
                acc[mt][nt] = __builtin_amdgcn_mfma_f32_16x16x32_bf16(afl[mt], bfh[nt], acc[mt][nt], 0,0,0);
            }
        __syncthreads();
    }

    #pragma unroll
    for (int mt=0; mt<4; mt++)
        #pragma unroll
        for (int nt=0; nt<4; nt++){
            int n = n0 + wn + nt*16 + l15;
            float bv = bias ? bias[n] : 0.f;
            #pragma unroll
            for (int r=0;r<4;r++){
                int m = m0 + wm + mt*16 + quad*4 + r;
                float v = acc[mt][nt][r] + bv;
                if (act==1) v = tanhf(v);
                C[(size_t)m*ldc + n] = v;
            }
        }
}

// ============ P[v][j] = char_emb(v,:) . Wih(j,:) + bih[j] + bhh[j], per dir ===========
__global__ void char_pmat(const float* __restrict__ ce,
                          const float* __restrict__ wf, const float* __restrict__ wb,
                          const float* __restrict__ bihF, const float* __restrict__ bhhF,
                          const float* __restrict__ bihB, const float* __restrict__ bhhB,
                          float* __restrict__ Pf, float* __restrict__ Pb)
{
    int gid = blockIdx.x*blockDim.x + threadIdx.x;
    if (gid >= 2*128*GC) return;
    int d = gid >> 16;
    int r = gid & 65535;
    int v = r >> 9, j = r & 511;
    const float* wW = d ? wb : wf;
    float s = 0.f;
    for (int e=0;e<EC;e++) s += ce[v*EC+e]*wW[j*EC+e];
    s += (d ? bihB[j]+bhhB[j] : bihF[j]+bhhF[j]);
    (d ? Pb : Pf)[r] = s;
}

__global__ void bias_sum(const float* __restrict__ a1, const float* __restrict__ a2,
                         const float* __restrict__ b1, const float* __restrict__ b2,
                         float* __restrict__ of, float* __restrict__ ob, int n)
{
    int i = blockIdx.x*blockDim.x+threadIdx.x;
    if (i < n){ of[i]=a1[i]+a2[i]; ob[i]=b1[i]+b2[i]; }
}

__global__ void zero_f(float* __restrict__ p, int n)
{
    int i = blockIdx.x*blockDim.x+threadIdx.x;
    if (i < n) p[i] = 0.f;
}

__global__ void split_pair(const float* __restrict__ src, u16* __restrict__ hi,
                           u16* __restrict__ lo, int n)
{
    int i = blockIdx.x*blockDim.x+threadIdx.x;
    if (i < n){ u16 h,l; split2(src[i],h,l); hi[i]=h; lo[i]=l; }
}

// pad word Wih (2048 x 557) -> hi/lo pairs (2048 x 576), zero tail
__global__ void pad_w_split(const float* __restrict__ wf, const float* __restrict__ wb,
                            u16* __restrict__ ofh, u16* __restrict__ ofl,
                            u16* __restrict__ obh, u16* __restrict__ obl)
{
    int gid = blockIdx.x*blockDim.x + threadIdx.x;
    if (gid >= 2*GW*DDP) return;
    int d = gid / (GW*DDP);
    int r = gid - d*(GW*DDP);
    int j = r / DDP, k = r - j*DDP;
    float v = (k < DD) ? (d ? wb[(size_t)j*DD+k] : wf[(size_t)j*DD+k]) : 0.f;
    u16 h,l; split2(v,h,l);
    if (d){ obh[r]=h; obl[r]=l; } else { ofh[r]=h; ofl[r]=l; }
}

// x assembly directly into bf16 pairs: word emb + cap + zero pad
__global__ void x_fill_pair(const int* __restrict__ wid, const int* __restrict__ cap,
                            const float* __restrict__ wemb, const float* __restrict__ cemb,
                            u16* __restrict__ Xh, u16* __restrict__ Xl)
{
    int gid = blockIdx.x*blockDim.x+threadIdx.x;
    int sb = gid / 320, e = gid - sb*320;
    if (sb >= NSB) return;
    float v; int col;
    if (e < 300){ v = wemb[(size_t)wid[sb]*300 + e]; col = e; }
    else if (e == 300){ v = cemb[cap[sb]]; col = 556; }
    else { v = 0.f; col = 556 + (e-300); }   // cols 557..575
    u16 h,l; split2(v,h,l);
    size_t idx = (size_t)sb*DDP + col;
    Xh[idx]=h; Xl[idx]=l;
}

// =================== char-LSTM step via MFMA (both dirs) — proven R6 ===================
__global__ __launch_bounds__(256, 2)
void char_step_mfma(const u16* __restrict__ cWFh, const u16* __restrict__ cWFl,
                    const u16* __restrict__ cWBh, const u16* __restrict__ cWBl,
                    const float* __restrict__ PF, const float* __restrict__ PB,
                    const int* __restrict__ ci,
                    u16* __restrict__ Hh, u16* __restrict__ Hl, float* __restrict__ Cc,
                    u16* __restrict__ Xh, u16* __restrict__ Xl, int kstep)
{
    const int dir = blockIdx.x >> 9;
    const int s0  = (blockIdx.x & 511) * 32;
    const int t = dir ? (WLEN-1-kstep) : kstep;
    const int islast = (kstep == WLEN-1);
    const u16* Wh = dir ? cWBh : cWFh;
    const u16* Wl = dir ? cWBl : cWFl;
    const float* P = dir ? PB : PF;
    u16* hh = Hh + (size_t)dir*NSEQ*HC;
    u16* hl = Hl + (size_t)dir*NSEQ*HC;
    float* cc = Cc + (size_t)dir*NSEQ*HC;

    __shared__ float zs[32*512];   // swizzled: idx = m*512 + ((col + 2m) & 511)

    const int tid = threadIdx.x;
    const int lane = tid & 63, wv = tid >> 6;
    const int quad = lane >> 4, l15 = lane & 15;
    const int n0w = wv * 128;

    f32x4 acc[2][8];
    #pragma unroll
    for (int i=0;i<2;i++)
        #pragma unroll
        for (int j=0;j<8;j++){ f32x4 z = {0.f,0.f,0.f,0.f}; acc[i][j] = z; }

    #pragma unroll
    for (int kc=0; kc<HC; kc+=32){
        bf16x8 ah[2], al[2];
        #pragma unroll
        for (int mt=0; mt<2; mt++){
            size_t p = (size_t)(s0 + mt*16 + l15)*HC + kc + quad*8;
            ah[mt] = *(const bf16x8*)&hh[p];
            al[mt] = *(const bf16x8*)&hl[p];
        }
        #pragma unroll
        for (int nt=0; nt<8; nt++){
            size_t p = (size_t)(n0w + nt*16 + l15)*HC + kc + quad*8;
            bf16x8 bh = *(const bf16x8*)&Wh[p];
            bf16x8 bl = *(const bf16x8*)&Wl[p];
            #pragma unroll
            for (int mt=0; mt<2; mt++){
                acc[mt][nt] = __builtin_amdgcn_mfma_f32_16x16x32_bf16(ah[mt], bh, acc[mt][nt], 0,0,0);
                acc[mt][nt] = __builtin_amdgcn_mfma_f32_16x16x32_bf16(ah[mt], bl, acc[mt][nt], 0,0,0);
                acc[mt][nt] = __builtin_amdgcn_mfma_f32_16x16x32_bf16(al[mt], bh, acc[mt][nt], 0,0,0);
            }
        }
    }

    #pragma unroll
    for (int mt=0; mt<2; mt++)
        #pragma unroll
        for (int nt=0; nt<8; nt++){
            int col = n0w + nt*16 + l15;
            #pragma unroll
            for (int r=0;r<4;r++){
                int m = mt*16 + quad*4 + r;
                zs[m*512 + ((col + 2*m) & 511)] = acc[mt][nt][r];
            }
        }
    __syncthreads();

    {
        int sl = tid >> 3, cg = tid & 7;
        int seq = s0 + sl;
        int cid = ci[seq*WLEN + t];
        const float* Pr = P + (size_t)cid*GC;
        int b = seq >> 8, s = seq & 255;
        size_t xbase = (size_t)(s*BATCH + b)*DDP + 300 + dir*HC;
        #pragma unroll
        for (int j=0;j<16;j++){
            int cell = cg*16 + j;
            float zi = zs[sl*512 + ((cell       + 2*sl) & 511)] + Pr[cell];
            float zf = zs[sl*512 + ((cell + 128 + 2*sl) & 511)] + Pr[128+cell];
            float zg = zs[sl*512 + ((cell + 256 + 2*sl) & 511)] + Pr[256+cell];
            float zo = zs[sl*512 + ((cell + 384 + 2*sl) & 511)] + Pr[384+cell];
            size_t ix = (size_t)seq*HC + cell;
            float cp = cc[ix];
            float cn = sigf(zf)*cp + sigf(zi)*tanhf(zg);
            float hv = sigf(zo)*tanhf(cn);
            cc[ix] = cn;
            u16 h_,l_; split2(hv,h_,l_);
            hh[ix]=h_; hl[ix]=l_;
            if (islast){ Xh[xbase+cell]=h_; Xl[xbase+cell]=l_; }
        }
    }
}

// =================== grid barrier (per-direction, 128 blocks) =========================
__device__ __forceinline__ void gridbar(unsigned* cnt, unsigned* gen, unsigned nb)
{
    __syncthreads();                         // drains block's vmem (waitcnt vmcnt(0))
    if (threadIdx.x == 0){
        __threadfence();                     // agent release: wbl2
        unsigned g = __hip_atomic_load(gen, __ATOMIC_RELAXED, __HIP_MEMORY_SCOPE_AGENT);
        unsigned a = __hip_atomic_fetch_add(cnt, 1u, __ATOMIC_ACQ_REL, __HIP_MEMORY_SCOPE_AGENT);
        if (a == nb - 1u){
            __hip_atomic_store(cnt, 0u, __ATOMIC_RELAXED, __HIP_MEMORY_SCOPE_AGENT);
            __hip_atomic_fetch_add(gen, 1u, __ATOMIC_ACQ_REL, __HIP_MEMORY_SCOPE_AGENT);
        } else {
            while (__hip_atomic_load(gen, __ATOMIC_ACQUIRE, __HIP_MEMORY_SCOPE_AGENT) == g){
                __builtin_amdgcn_s_sleep(1);
            }
        }
        __threadfence();                     // agent acquire: invalidate
    }
    __syncthreads();
}

// =================== persistent word-LSTM scan (SCHUNK steps, both dirs) ==============
// grid 256 = dir(2) x cellgroup(128, 4 cells each). Block: 4 waves; wave = 16-batch tile.
// Whh slice (16 gate rows x 512 K, hi+lo) resident in VGPRs. c-state in registers.
// h state in global bf16 pairs, parity double-buffered; grid barrier between steps.
__global__ __launch_bounds__(256, 1)
void word_scan(const float* __restrict__ AxF, const float* __restrict__ AxB,
               const u16* __restrict__ wrFh, const u16* __restrict__ wrFl,
               const u16* __restrict__ wrBh, const u16* __restrict__ wrBl,
               u16* __restrict__ HPh, u16* __restrict__ HPl,   // [par][dir][64][512]
               float* __restrict__ CW,                          // [dir][64*512]
               u16* __restrict__ Eh, u16* __restrict__ El,
               unsigned* __restrict__ bar, int jc)
{
    const int blk = blockIdx.x;
    const int dir = blk >> 7;
    const int c0  = (blk & 127) * 4;
    const float* Ax = dir ? AxB : AxF;
    const u16* Wh = dir ? wrBh : wrFh;
    const u16* Wl = dir ? wrBl : wrFl;
    unsigned* cnt = bar + dir*32;
    unsigned* gen = bar + dir*32 + 16;

    __shared__ float zsc[4][16][17];

    const int tid = threadIdx.x;
    const int lane = tid & 63, wv = tid >> 6;
    const int quad = lane >> 4, l15 = lane & 15;

    // B fragments: lane l15 -> gate row r=l15; Whh row j = (r>>2)*512 + c0 + (r&3)
    const size_t jrow = (size_t)((l15 >> 2)*HWID + c0 + (l15 & 3)) * HWID;
    bf16x8 bh[16], bl[16];
    #pragma unroll
    for (int kc=0; kc<16; kc++){
        bh[kc] = *(const bf16x8*)&Wh[jrow + kc*32 + quad*8];
        bl[kc] = *(const bf16x8*)&Wl[jrow + kc*32 + quad*8];
    }

    const int batch = wv*16 + l15;      // A-side M row (MFMA) and pointwise batch
    const int cell  = c0 + quad;        // pointwise cell
    float creg = CW[dir*(BATCH*HWID) + batch*HWID + cell];
    const size_t abase = (size_t)batch*HWID + quad*8;

    // Ax prefetch for t=0
    float ax0, ax1, ax2, ax3;
    {
        const int lr0 = dir ? (SCHUNK-1) : 0;
        const float* axp = Ax + ((size_t)(lr0*BATCH + batch))*GW + cell;
        ax0 = axp[0]; ax1 = axp[HWID]; ax2 = axp[2*HWID]; ax3 = axp[3*HWID];
    }

    for (int t=0; t<SCHUNK; t++){
        const int ss = jc*SCHUNK + t;
        const int s  = dir ? (S_LEN-1-ss) : ss;
        const int par = t & 1;
        const u16* hh = HPh + ((size_t)(par*2 + dir))*(BATCH*HWID);
        const u16* hl = HPl + ((size_t)(par*2 + dir))*(BATCH*HWID);

        f32x4 acc = {0.f,0.f,0.f,0.f};
        #pragma unroll
        for (int kc=0; kc<16; kc++){
            bf16x8 ah = *(const bf16x8*)&hh[abase + kc*32];
            bf16x8 al = *(const bf16x8*)&hl[abase + kc*32];
            acc = __builtin_amdgcn_mfma_f32_16x16x32_bf16(ah, bh[kc], acc, 0,0,0);
            acc = __builtin_amdgcn_mfma_f32_16x16x32_bf16(ah, bl[kc], acc, 0,0,0);
            acc = __builtin_amdgcn_mfma_f32_16x16x32_bf16(al, bh[kc], acc, 0,0,0);
        }
        // z roundtrip (per-wave LDS region; DS ops in-order within wave)
        #pragma unroll
        for (int i=0;i<4;i++) zsc[wv][quad*4+i][l15] = acc[i];
        float zi = zsc[wv][l15][quad]     + ax0;
        float zf = zsc[wv][l15][4+quad]   + ax1;
        float zg = zsc[wv][l15][8+quad]   + ax2;
        float zo = zsc[wv][l15][12+quad]  + ax3;
        float cn = sigf(zf)*creg + sigf(zi)*tanhf(zg);
        creg = cn;
        float hv = sigf(zo)*tanhf(cn);
        u16 h_, l_; split2(hv, h_, l_);
        u16* nh = HPh + ((size_t)((1-par)*2 + dir))*(BATCH*HWID);
        u16* nl = HPl + ((size_t)((1-par)*2 + dir))*(BATCH*HWID);
        nh[batch*HWID + cell] = h_;
        nl[batch*HWID + cell] = l_;
        size_t ei = ((size_t)(s*BATCH + batch))*(2*HWID) + dir*HWID + cell;
        Eh[ei] = h_; El[ei] = l_;

        if (t < SCHUNK-1){
            // prefetch Ax for t+1 (static data; overlaps barrier spin)
            const int lr = dir ? (SCHUNK-2-t) : (t+1);
            const float* axp = Ax + ((size_t)(lr*BATCH + batch))*GW + cell;
            ax0 = axp[0]; ax1 = axp[HWID]; ax2 = axp[2*HWID]; ax3 = axp[3*HWID];
            gridbar(cnt, gen, 128u);
        }
    }
    CW[dir*(BATCH*HWID) + batch*HWID + cell] = creg;
}

// ---------------- CRF log-likelihood (one wave per batch) ------------------------------
__global__ __launch_bounds__(64)
void crf_loss(const float* __restrict__ logits, const int* __restrict__ tags,
              const float* __restrict__ trans, const float* __restrict__ start,
              const float* __restrict__ endt, float* __restrict__ out)
{
    int b = blockIdx.x, lane = threadIdx.x;
    __shared__ float trs[TT*TT];
    __shared__ float as_[TT];
    __shared__ float red[64];
    for (int i=lane;i<TT*TT;i+=64) trs[i]=trans[i];
    __syncthreads();
    float alpha = (lane<TT) ? (start[lane] + logits[b*TT + lane]) : -1e30f;
    for (int s=1;s<S_LEN;s++){
        if (lane<TT) as_[lane]=alpha;
        __syncthreads();
        if (lane<TT){
            float m = -1e30f;
            for (int f=0;f<TT;f++){ float v=as_[f]+trs[f*TT+lane]; m = fmaxf(m,v); }
            float sm = 0.f;
            for (int f=0;f<TT;f++){ float v=as_[f]+trs[f*TT+lane]; sm += __expf(v-m); }
            alpha = m + __logf(sm) + logits[((size_t)s*BATCH+b)*TT + lane];
        }
        __syncthreads();
    }
    if (lane<TT) red[lane] = alpha + endt[lane];
    __syncthreads();
    float logZ = 0.f;
    if (lane==0){
        float m=-1e30f; for(int i=0;i<TT;i++) m=fmaxf(m,red[i]);
        float sm=0.f;   for(int i=0;i<TT;i++) sm += __expf(red[i]-m);
        logZ = m + __logf(sm);
    }
    __syncthreads();
    float sc = 0.f;
    for (int s=lane;s<S_LEN;s+=64){
        int tg = tags[s*BATCH+b];
        sc += logits[((size_t)s*BATCH+b)*TT + tg];
        if (s+1 < S_LEN){ int t2 = tags[(s+1)*BATCH+b]; sc += trs[tg*TT+t2]; }
    }
    red[lane]=sc; __syncthreads();
    if (lane==0){
        float tot = 0.f; for (int i=0;i<64;i++) tot += red[i];
        tot += start[tags[b]] + endt[tags[(S_LEN-1)*BATCH + b]];
        atomicAdd(out, -(tot - logZ));
    }
}

// ---------------- Viterbi (one wave per batch) -----------------------------------------
__global__ __launch_bounds__(64)
void viterbi_k(const float* __restrict__ logits, const float* __restrict__ trans,
               const float* __restrict__ start, const float* __restrict__ endt,
               int* __restrict__ bp, float* __restrict__ outTags)
{
    int b = blockIdx.x, lane = threadIdx.x;
    __shared__ float trs[TT*TT];
    __shared__ float vs_[TT];
    for (int i=lane;i<TT*TT;i+=64) trs[i]=trans[i];
    __syncthreads();
    float v = (lane<TT) ? (start[lane] + logits[b*TT+lane]) : -1e30f;
    for (int s=1;s<S_LEN;s++){
        if (lane<TT) vs_[lane]=v;
        __syncthreads();
        if (lane<TT){
            float best=-1e30f; int bj=0;
            for (int f=0;f<TT;f++){
                float val = vs_[f]+trs[f*TT+lane];
                if (val > best){ best=val; bj=f; }
            }
            v = best + logits[((size_t)s*BATCH+b)*TT+lane];
            bp[((size_t)(s-1)*BATCH+b)*TT + lane] = bj;
        }
        __syncthreads();
    }
    if (lane<TT) vs_[lane] = v + endt[lane];
    __syncthreads();
    if (lane==0){
        float best=-1e30f; int last=0;
        for (int i=0;i<TT;i++){ if (vs_[i] > best){best=vs_[i]; last=i;} }
        int tag=last;
        outTags[b*S_LEN + (S_LEN-1)] = (float)tag;
        for (int s=S_LEN-2;s>=0;s--){
            tag = bp[((size_t)s*BATCH+b)*TT + tag];
            outTags[b*S_LEN + s] = (float)tag;
        }
    }
}

// ======================================================================================
extern "C" void kernel_launch(void* const* d_in, const int* in_sizes, int n_in,
                              void* d_out, int out_size, void* d_ws, size_t ws_size,
                              hipStream_t stream)
{
    const int* word_in = (const int*)d_in[0];
    const int* char_in = (const int*)d_in[1];
    const int* cap_in  = (const int*)d_in[2];
    const int* tag_in  = (const int*)d_in[3];
    const float* wemb  = (const float*)d_in[4];
    const float* cemb  = (const float*)d_in[5];
    const float* chemb = (const float*)d_in[6];
    const float* cWihF=(const float*)d_in[7],  *cWhhF=(const float*)d_in[8];
    const float* cBihF=(const float*)d_in[9],  *cBhhF=(const float*)d_in[10];
    const float* cWihB=(const float*)d_in[11], *cWhhB=(const float*)d_in[12];
    const float* cBihB=(const float*)d_in[13], *cBhhB=(const float*)d_in[14];
    const float* wWihF=(const float*)d_in[15], *wWhhF=(const float*)d_in[16];
    const float* wBihF=(const float*)d_in[17], *wBhhF=(const float*)d_in[18];
    const float* wWihB=(const float*)d_in[19], *wWhhB=(const float*)d_in[20];
    const float* wBihB=(const float*)d_in[21], *wBhhB=(const float*)d_in[22];
    const float* ff1W=(const float*)d_in[23],  *ff1b=(const float*)d_in[24];
    const float* ff2W=(const float*)d_in[25],  *ff2b=(const float*)d_in[26];
    const float* trans=(const float*)d_in[27];
    const float* startT=(const float*)d_in[28], *endT=(const float*)d_in[29];
    float* out = (float*)d_out;

    // ---- workspace layout (fl units), ~143 MB ------------------------------
    float* W = (float*)d_ws;
    size_t o = 0;
    float* XhF  = W + o; o += (size_t)NSB*DDP/2;      // X hi pairs (u16)
    float* XlF  = W + o; o += (size_t)NSB*DDP/2;
    float* AXCF = W + o; o += (size_t)CROWS*GW;       // 2.1M fl
    float* AXCB = W + o; o += (size_t)CROWS*GW;
    float* EhF  = W + o; o += (size_t)NSB*1024/2;     // ENC hi pairs
    float* ElF  = W + o; o += (size_t)NSB*1024/2;
    float* PF   = W + o; o += 128*GC;
    float* PB   = W + o; o += 128*GC;
    float* BSF  = W + o; o += GW;
    float* BSB  = W + o; o += GW;
    float* CWb  = W + o; o += (size_t)2*BATCH*HWID;   // word c state
    float* WFh  = W + o; o += (size_t)GW*DDP/2;       // word Wih pairs
    float* WFl  = W + o; o += (size_t)GW*DDP/2;
    float* WBh  = W + o; o += (size_t)GW*DDP/2;
    float* WBl  = W + o; o += (size_t)GW*DDP/2;
    float* cFh  = W + o; o += (size_t)GC*HC/2;        // char Whh pairs
    float* cFl  = W + o; o += (size_t)GC*HC/2;
    float* cBh  = W + o; o += (size_t)GC*HC/2;
    float* cBl  = W + o; o += (size_t)GC*HC/2;
    float* f1h  = W + o; o += (size_t)HWID*1024/2;    // ff1W pairs
    float* f1l  = W + o; o += (size_t)HWID*1024/2;
    float* wrFhF= W + o; o += (size_t)GW*HWID/2;      // word Whh pairs
    float* wrFlF= W + o; o += (size_t)GW*HWID/2;
    float* wrBhF= W + o; o += (size_t)GW*HWID/2;
    float* wrBlF= W + o; o += (size_t)GW*HWID/2;
    float* HPhF = W + o; o += (size_t)2*2*BATCH*HWID/2;  // h pairs hi [par][dir][64][512]
    float* HPlF = W + o; o += (size_t)2*2*BATCH*HWID/2;  // h pairs lo (adjacent to HPhF)
    float* barF = W + o; o += 64;

    u16* Xh = (u16*)XhF;  u16* Xl = (u16*)XlF;
    u16* Eh = (u16*)EhF;  u16* El = (u16*)ElF;
    // char state aliases inside ENC region (disjoint in time)
    u16*   Hh = (u16*)EhF;
    u16*   Hl = (u16*)(EhF + (size_t)NSEQ*HC);
    float* Cc = EhF + (size_t)2*NSEQ*HC;
    float* HFF = AXCF;                  // ff1 hidden (spans AXCF+AXCB: 4.2M >= 2.1M... )
    float* LOG = XhF;                   // logits, after X dead
    int*   BP  = (int*)(XhF + (size_t)NSB*TT);
    unsigned* bar = (unsigned*)barF;

    dim3 blk(256);

    // ---- precomputes -------------------------------------------------------
    char_pmat<<<(2*128*GC+255)/256, blk, 0, stream>>>(chemb, cWihF, cWihB,
                                                      cBihF, cBhhF, cBihB, cBhhB, PF, PB);
    x_fill_pair<<<((size_t)NSB*320+255)/256, blk, 0, stream>>>(word_in, cap_in, wemb, cemb, Xh, Xl);
    bias_sum<<<(GW+255)/256, blk, 0, stream>>>(wBihF, wBhhF, wBihB, wBhhB, BSF, BSB, GW);
    pad_w_split<<<(2*GW*DDP+255)/256, blk, 0, stream>>>(wWihF, wWihB,
                                                        (u16*)WFh,(u16*)WFl,(u16*)WBh,(u16*)WBl);
    split_pair<<<(GC*HC+255)/256, blk, 0, stream>>>(cWhhF, (u16*)cFh, (u16*)cFl, GC*HC);
    split_pair<<<(GC*HC+255)/256, blk, 0, stream>>>(cWhhB, (u16*)cBh, (u16*)cBl, GC*HC);
    split_pair<<<(HWID*1024+255)/256, blk, 0, stream>>>(ff1W, (u16*)f1h, (u16*)f1l, HWID*1024);
    split_pair<<<(GW*HWID+255)/256, blk, 0, stream>>>(wWhhF, (u16*)wrFhF, (u16*)wrFlF, GW*HWID);
    split_pair<<<(GW*HWID+255)/256, blk, 0, stream>>>(wWhhB, (u16*)wrBhF, (u16*)wrBlF, GW*HWID);

    // ---- char BiLSTM (MFMA) ------------------------------------------------
    zero_f<<<((size_t)NSB*1024/2+255)/256, blk, 0, stream>>>(EhF, NSB*1024/2); // h/c init
    for (int k=0;k<WLEN;k++){
        char_step_mfma<<<1024, blk, 0, stream>>>((u16*)cFh,(u16*)cFl,(u16*)cBh,(u16*)cBl,
                                                 PF, PB, char_in, Hh, Hl, Cc, Xh, Xl, k);
    }

    // ---- word BiLSTM: chunked Ax GEMM + persistent scan --------------------
    zero_f<<<(2*BATCH*HWID+255)/256, blk, 0, stream>>>(CWb, 2*BATCH*HWID);
    zero_f<<<(2*2*BATCH*HWID/2*2+255)/256, blk, 0, stream>>>(HPhF, 2*2*BATCH*HWID/2*2); // HPh+HPl
    zero_f<<<1, dim3(64), 0, stream>>>(barF, 64);
    dim3 gax(CROWS/128, GW/128);   // (8, 16)
    for (int j=0;j<S_LEN/SCHUNK;j++){
        int sbf = j*SCHUNK;
        int sbb = (S_LEN-SCHUNK) - j*SCHUNK;
        gemm_mfma<<<gax, blk, 0, stream>>>(Xh + (size_t)sbf*BATCH*DDP, Xl + (size_t)sbf*BATCH*DDP, DDP,
                                           (u16*)WFh, (u16*)WFl, DDP,
                                           AXCF, GW, DDP, BSF, 0);
        gemm_mfma<<<gax, blk, 0, stream>>>(Xh + (size_t)sbb*BATCH*DDP, Xl + (size_t)sbb*BATCH*DDP, DDP,
                                           (u16*)WBh, (u16*)WBl, DDP,
                                           AXCB, GW, DDP, BSB, 0);
        word_scan<<<256, blk, 0, stream>>>(AXCF, AXCB,
                                           (u16*)wrFhF, (u16*)wrFlF, (u16*)wrBhF, (u16*)wrBlF,
                                           (u16*)HPhF, (u16*)HPlF, CWb, Eh, El, bar, j);
    }

    // ---- feed-forward head -------------------------------------------------
    dim3 g1(NSB/128, HWID/128);    // (128, 4)
    gemm_mfma<<<g1, blk, 0, stream>>>(Eh, El, 1024, (u16*)f1h, (u16*)f1l, 1024,
                                      HFF, HWID, 1024, ff1b, 1);
    dim3 g2(NSB/128, 1);
    gemm128<<<g2, blk, 0, stream>>>(HFF, HWID, ff2W, HWID, LOG, TT,
                                    NSB, TT, HWID, ff2b, 0);

    // ---- CRF loss + Viterbi ------------------------------------------------
    zero_f<<<1, dim3(64), 0, stream>>>(out, 1);
    crf_loss<<<BATCH, dim3(64), 0, stream>>>(LOG, tag_in, trans, startT, endT, out);
    viterbi_k<<<BATCH, dim3(64), 0, stream>>>(LOG, trans, startT, endT, BP, out+1);
}

// Round 8
// 6092.585 us; speedup vs baseline: 2.2008x; 2.2008x over previous
//
#include <hip/hip_runtime.h>
#include <math.h>

// Problem constants
#define S_LEN 256
#define BATCH 64
#define WLEN  16
#define EC    64
#define HC    128
#define HWID  512
#define TT    32
#define DD    557
#define DDP   576    // padded K for MFMA (mult of 32)
#define NSEQ  16384
#define NSB   16384
#define GC    512    // 4*HC
#define GW    2048   // 4*HWID
#define SCHUNK 16
#define CROWS (SCHUNK*BATCH)   // 1024

typedef unsigned short u16;
typedef unsigned int u32;
typedef unsigned long long u64;
typedef __attribute__((ext_vector_type(8))) short bf16x8;
typedef __attribute__((ext_vector_type(4))) float f32x4;

__device__ __forceinline__ float sigf(float x){ return 1.f/(1.f+__expf(-x)); }

// split fp32 -> (hi, lo) bf16 by bit truncation; v ~= hi + lo with ~16 mantissa bits
__device__ __forceinline__ void split2(float v, u16& h, u16& l){
    unsigned int u = __float_as_uint(v);
    h = (u16)(u >> 16);
    float r = v - __uint_as_float(u & 0xffff0000u);
    l = (u16)(__float_as_uint(r) >> 16);
}

// =================== fp32 GEMM (kept for ff2, small N) ================================
#define BM 128
#define BN 128
#define BK 16
__global__ __launch_bounds__(256, 2)
void gemm128(const float* __restrict__ A, int lda,
             const float* __restrict__ Bm, int ldb,
             float* __restrict__ C, int ldc,
             int M, int N, int K,
             const float* __restrict__ bias, int act)
{
    __shared__ float As[BK][BM+4];
    __shared__ float Bs[BK][BN+4];
    const int tid = threadIdx.x;
    const int m0 = blockIdx.x * BM;
    const int n0 = blockIdx.y * BN;
    const int tr = tid >> 4;
    const int tc = tid & 15;
    float acc[8][8];
    #pragma unroll
    for (int i=0;i<8;i++)
        #pragma unroll
        for(int j=0;j<8;j++) acc[i][j]=0.f;

    for (int k0 = 0; k0 < K; k0 += BK) {
        #pragma unroll
        for (int i=0;i<2;i++){
            int e = i*256 + tid;
            int m = e >> 2, kq = e & 3;
            int gm = m0 + m;
            float4 v = make_float4(0.f,0.f,0.f,0.f);
            if (gm < M) v = *(const float4*)&A[(size_t)gm*lda + k0 + kq*4];
            As[kq*4+0][m]=v.x; As[kq*4+1][m]=v.y; As[kq*4+2][m]=v.z; As[kq*4+3][m]=v.w;
        }
        #pragma unroll
        for (int i=0;i<2;i++){
            int e = i*256 + tid;
            int n = e >> 2, kq = e & 3;
            int gn = n0 + n;
            float4 v = make_float4(0.f,0.f,0.f,0.f);
            if (gn < N) v = *(const float4*)&Bm[(size_t)gn*ldb + k0 + kq*4];
            Bs[kq*4+0][n]=v.x; Bs[kq*4+1][n]=v.y; Bs[kq*4+2][n]=v.z; Bs[kq*4+3][n]=v.w;
        }
        __syncthreads();
        #pragma unroll
        for (int k = 0; k < BK; k++) {
            float4 a0 = *(float4*)&As[k][tr*8];
            float4 a1 = *(float4*)&As[k][tr*8+4];
            float4 b0 = *(float4*)&Bs[k][tc*8];
            float4 b1 = *(float4*)&Bs[k][tc*8+4];
            float av[8] = {a0.x,a0.y,a0.z,a0.w,a1.x,a1.y,a1.z,a1.w};
            float bv[8] = {b0.x,b0.y,b0.z,b0.w,b1.x,b1.y,b1.z,b1.w};
            #pragma unroll
            for (int i=0;i<8;i++)
                #pragma unroll
                for (int j=0;j<8;j++)
                    acc[i][j] += av[i]*bv[j];
        }
        __syncthreads();
    }
    #pragma unroll
    for (int i=0;i<8;i++){
        int m = m0 + tr*8 + i;
        if (m >= M) continue;
        #pragma unroll
        for (int j=0;j<8;j++){
            int n = n0 + tc*8 + j;
            if (n >= N) continue;
            float v = acc[i][j];
            if (bias) v += bias[n];
            if (act==1) v = tanhf(v);
            C[(size_t)m*ldc + n] = v;
        }
    }
}

// ============ MFMA split-bf16 GEMM: C = act(A(MxK)*B(NxK)^T + bias) ===================
__global__ __launch_bounds__(256, 2)
void gemm_mfma(const u16* __restrict__ Ah, const u16* __restrict__ Al, int lda,
               const u16* __restrict__ Bh, const u16* __restrict__ Bl, int ldb,
               float* __restrict__ C, int ldc, int K,
               const float* __restrict__ bias, int act)
{
    __shared__ u16 AsH[128*40], AsL[128*40], BsH[128*40], BsL[128*40];
    const int tid  = threadIdx.x;
    const int lane = tid & 63, wv = tid >> 6;
    const int m0 = blockIdx.x * 128, n0 = blockIdx.y * 128;
    const int wm = (wv >> 1) * 64, wn = (wv & 1) * 64;
    const int quad = lane >> 4, l15 = lane & 15;
    const int sr = tid >> 1;            // staging row 0..127
    const int sh = (tid & 1) * 16;      // staging k-half: u16 offset 0 or 16

    f32x4 acc[4][4];
    #pragma unroll
    for (int i=0;i<4;i++)
        #pragma unroll
        for (int j=0;j<4;j++){ f32x4 z = {0.f,0.f,0.f,0.f}; acc[i][j] = z; }

    for (int kc = 0; kc < K; kc += 32){
        const size_t ra = (size_t)(m0+sr)*lda + kc + sh;
        const size_t rb = (size_t)(n0+sr)*ldb + kc + sh;
        uint4 a0 = *(const uint4*)&Ah[ra];
        uint4 a1 = *(const uint4*)&Ah[ra + 8];
        uint4 l0 = *(const uint4*)&Al[ra];
        uint4 l1 = *(const uint4*)&Al[ra + 8];
        uint4 b0 = *(const uint4*)&Bh[rb];
        uint4 b1 = *(const uint4*)&Bh[rb + 8];
        uint4 c0 = *(const uint4*)&Bl[rb];
        uint4 c1 = *(const uint4*)&Bl[rb + 8];
        *(uint4*)&AsH[sr*40 + sh]     = a0;
        *(uint4*)&AsH[sr*40 + sh + 8] = a1;
        *(uint4*)&AsL[sr*40 + sh]     = l0;
        *(uint4*)&AsL[sr*40 + sh + 8] = l1;
        *(uint4*)&BsH[sr*40 + sh]     = b0;
        *(uint4*)&BsH[sr*40 + sh + 8] = b1;
        *(uint4*)&BsL[sr*40 + sh]     = c0;
        *(uint4*)&BsL[sr*40 + sh + 8] = c1;
        __syncthreads();

        bf16x8 afh[4], afl[4], bfh[4], bfl[4];
        #pragma unroll
        for (int mt=0; mt<4; mt++){
            int r = wm + mt*16 + l15;
            afh[mt] = *(const bf16x8*)&AsH[r*40 + quad*8];
            afl[mt] = *(const bf16x8*)&AsL[r*40 + quad*8];
        }
        #pragma unroll
        for (int nt=0; nt<4; nt++){
            int r = wn + nt*16 + l15;
            bfh[nt] = *(const bf16x8*)&BsH[r*40 + quad*8];
            bfl[nt] = *(const bf16x8*)&BsL[r*40 + quad*8];
        }
        #pragma unroll
        for (int mt=0; mt<4; mt++)
            #pragma unroll
            for (int nt=0; nt<4; nt++){
                acc[mt][nt] = __builtin_amdgcn_mfma_f32_16x16x32_bf16(afh[mt], bfh[nt], acc[mt][nt], 0,0,0);
                acc[mt][nt] = __builtin_amdgcn_mfma_f32_16x16x32_bf16(afh[mt], bfl[nt], acc[mt][nt], 0,0,0);
                acc[mt][nt] = __builtin_amdgcn_mfma_f32_16x16x32_bf16(afl[mt], bfh[nt], acc[mt][nt], 0,0,0);
            }
        __syncthreads();
    }

    #pragma unroll
    for (int mt=0; mt<4; mt++)
        #pragma unroll
        for (int nt=0; nt<4; nt++){
            int n = n0 + wn + nt*16 + l15;
            float bv = bias ? bias[n] : 0.f;
            #pragma unroll
            for (int r=0;r<4;r++){
                int m = m0 + wm + mt*16 + quad*4 + r;
                float v = acc[mt][nt][r] + bv;
                if (act==1) v = tanhf(v);
                C[(size_t)m*ldc + n] = v;
            }
        }
}

// ============ P[v][j] = char_emb(v,:) . Wih(j,:) + bih[j] + bhh[j], per dir ===========
__global__ void char_pmat(const float* __restrict__ ce,
                          const float* __restrict__ wf, const float* __restrict__ wb,
                          const float* __restrict__ bihF, const float* __restrict__ bhhF,
                          const float* __restrict__ bihB, const float* __restrict__ bhhB,
                          float* __restrict__ Pf, float* __restrict__ Pb)
{
    int gid = blockIdx.x*blockDim.x + threadIdx.x;
    if (gid >= 2*128*GC) return;
    int d = gid >> 16;
    int r = gid & 65535;
    int v = r >> 9, j = r & 511;
    const float* wW = d ? wb : wf;
    float s = 0.f;
    for (int e=0;e<EC;e++) s += ce[v*EC+e]*wW[j*EC+e];
    s += (d ? bihB[j]+bhhB[j] : bihF[j]+bhhF[j]);
    (d ? Pb : Pf)[r] = s;
}

__global__ void bias_sum(const float* __restrict__ a1, const float* __restrict__ a2,
                         const float* __restrict__ b1, const float* __restrict__ b2,
                         float* __restrict__ of, float* __restrict__ ob, int n)
{
    int i = blockIdx.x*blockDim.x+threadIdx.x;
    if (i < n){ of[i]=a1[i]+a2[i]; ob[i]=b1[i]+b2[i]; }
}

__global__ void zero_f(float* __restrict__ p, int n)
{
    int i = blockIdx.x*blockDim.x+threadIdx.x;
    if (i < n) p[i] = 0.f;
}

__global__ void split_pair(const float* __restrict__ src, u16* __restrict__ hi,
                           u16* __restrict__ lo, int n)
{
    int i = blockIdx.x*blockDim.x+threadIdx.x;
    if (i < n){ u16 h,l; split2(src[i],h,l); hi[i]=h; lo[i]=l; }
}

// pad word Wih (2048 x 557) -> hi/lo pairs (2048 x 576), zero tail
__global__ void pad_w_split(const float* __restrict__ wf, const float* __restrict__ wb,
                            u16* __restrict__ ofh, u16* __restrict__ ofl,
                            u16* __restrict__ obh, u16* __restrict__ obl)
{
    int gid = blockIdx.x*blockDim.x + threadIdx.x;
    if (gid >= 2*GW*DDP) return;
    int d = gid / (GW*DDP);
    int r = gid - d*(GW*DDP);
    int j = r / DDP, k = r - j*DDP;
    float v = (k < DD) ? (d ? wb[(size_t)j*DD+k] : wf[(size_t)j*DD+k]) : 0.f;
    u16 h,l; split2(v,h,l);
    if (d){ obh[r]=h; obl[r]=l; } else { ofh[r]=h; ofl[r]=l; }
}

// x assembly directly into bf16 pairs: word emb + cap + zero pad
__global__ void x_fill_pair(const int* __restrict__ wid, const int* __restrict__ cap,
                            const float* __restrict__ wemb, const float* __restrict__ cemb,
                            u16* __restrict__ Xh, u16* __restrict__ Xl)
{
    int gid = blockIdx.x*blockDim.x+threadIdx.x;
    int sb = gid / 320, e = gid - sb*320;
    if (sb >= NSB) return;
    float v; int col;
    if (e < 300){ v = wemb[(size_t)wid[sb]*300 + e]; col = e; }
    else if (e == 300){ v = cemb[cap[sb]]; col = 556; }
    else { v = 0.f; col = 556 + (e-300); }   // cols 557..575
    u16 h,l; split2(v,h,l);
    size_t idx = (size_t)sb*DDP + col;
    Xh[idx]=h; Xl[idx]=l;
}

// =================== char-LSTM step via MFMA (both dirs) — proven R6 ===================
__global__ __launch_bounds__(256, 2)
void char_step_mfma(const u16* __restrict__ cWFh, const u16* __restrict__ cWFl,
                    const u16* __restrict__ cWBh, const u16* __restrict__ cWBl,
                    const float* __restrict__ PF, const float* __restrict__ PB,
                    const int* __restrict__ ci,
                    u16* __restrict__ Hh, u16* __restrict__ Hl, float* __restrict__ Cc,
                    u16* __restrict__ Xh, u16* __restrict__ Xl, int kstep)
{
    const int dir = blockIdx.x >> 9;
    const int s0  = (blockIdx.x & 511) * 32;
    const int t = dir ? (WLEN-1-kstep) : kstep;
    const int islast = (kstep == WLEN-1);
    const u16* Wh = dir ? cWBh : cWFh;
    const u16* Wl = dir ? cWBl : cWFl;
    const float* P = dir ? PB : PF;
    u16* hh = Hh + (size_t)dir*NSEQ*HC;
    u16* hl = Hl + (size_t)dir*NSEQ*HC;
    float* cc = Cc + (size_t)dir*NSEQ*HC;

    __shared__ float zs[32*512];   // swizzled: idx = m*512 + ((col + 2m) & 511)

    const int tid = threadIdx.x;
    const int lane = tid & 63, wv = tid >> 6;
    const int quad = lane >> 4, l15 = lane & 15;
    const int n0w = wv * 128;

    f32x4 acc[2][8];
    #pragma unroll
    for (int i=0;i<2;i++)
        #pragma unroll
        for (int j=0;j<8;j++){ f32x4 z = {0.f,0.f,0.f,0.f}; acc[i][j] = z; }

    #pragma unroll
    for (int kc=0; kc<HC; kc+=32){
        bf16x8 ah[2], al[2];
        #pragma unroll
        for (int mt=0; mt<2; mt++){
            size_t p = (size_t)(s0 + mt*16 + l15)*HC + kc + quad*8;
            ah[mt] = *(const bf16x8*)&hh[p];
            al[mt] = *(const bf16x8*)&hl[p];
        }
        #pragma unroll
        for (int nt=0; nt<8; nt++){
            size_t p = (size_t)(n0w + nt*16 + l15)*HC + kc + quad*8;
            bf16x8 bh = *(const bf16x8*)&Wh[p];
            bf16x8 bl = *(const bf16x8*)&Wl[p];
            #pragma unroll
            for (int mt=0; mt<2; mt++){
                acc[mt][nt] = __builtin_amdgcn_mfma_f32_16x16x32_bf16(ah[mt], bh, acc[mt][nt], 0,0,0);
                acc[mt][nt] = __builtin_amdgcn_mfma_f32_16x16x32_bf16(ah[mt], bl, acc[mt][nt], 0,0,0);
                acc[mt][nt] = __builtin_amdgcn_mfma_f32_16x16x32_bf16(al[mt], bh, acc[mt][nt], 0,0,0);
            }
        }
    }

    #pragma unroll
    for (int mt=0; mt<2; mt++)
        #pragma unroll
        for (int nt=0; nt<8; nt++){
            int col = n0w + nt*16 + l15;
            #pragma unroll
            for (int r=0;r<4;r++){
                int m = mt*16 + quad*4 + r;
                zs[m*512 + ((col + 2*m) & 511)] = acc[mt][nt][r];
            }
        }
    __syncthreads();

    {
        int sl = tid >> 3, cg = tid & 7;
        int seq = s0 + sl;
        int cid = ci[seq*WLEN + t];
        const float* Pr = P + (size_t)cid*GC;
        int b = seq >> 8, s = seq & 255;
        size_t xbase = (size_t)(s*BATCH + b)*DDP + 300 + dir*HC;
        #pragma unroll
        for (int j=0;j<16;j++){
            int cell = cg*16 + j;
            float zi = zs[sl*512 + ((cell       + 2*sl) & 511)] + Pr[cell];
            float zf = zs[sl*512 + ((cell + 128 + 2*sl) & 511)] + Pr[128+cell];
            float zg = zs[sl*512 + ((cell + 256 + 2*sl) & 511)] + Pr[256+cell];
            float zo = zs[sl*512 + ((cell + 384 + 2*sl) & 511)] + Pr[384+cell];
            size_t ix = (size_t)seq*HC + cell;
            float cp = cc[ix];
            float cn = sigf(zf)*cp + sigf(zi)*tanhf(zg);
            float hv = sigf(zo)*tanhf(cn);
            cc[ix] = cn;
            u16 h_,l_; split2(hv,h_,l_);
            hh[ix]=h_; hl[ix]=l_;
            if (islast){ Xh[xbase+cell]=h_; Xl[xbase+cell]=l_; }
        }
    }
}

// =================== flag-array grid barrier (per-direction, 128 blocks) ==============
// No fences: all cross-block data (h) moves via agent-scope cache-bypass atomics, so
// only ordering needed is "h stores drained (vmcnt0 at __syncthreads) before flag set".
// All atomics RELAXED — an ACQUIRE here would emit buffer_inv and kill the warm L1.
__device__ __forceinline__ void gridbar2(u32* fl_, u32* gn_, int part, u32 target)
{
    __syncthreads();                          // drains this block's h atomic stores
    if (part == 0){
        int t = threadIdx.x;
        if (t >= 1 && t < 128){
            while (__hip_atomic_load(&fl_[t*32], __ATOMIC_RELAXED, __HIP_MEMORY_SCOPE_AGENT) < target)
                __builtin_amdgcn_s_sleep(2);
        }
        __syncthreads();
        if (t == 0)
            __hip_atomic_store(gn_, target, __ATOMIC_RELAXED, __HIP_MEMORY_SCOPE_AGENT);
    } else {
        if (threadIdx.x == 0){
            __hip_atomic_store(&fl_[part*32], target, __ATOMIC_RELAXED, __HIP_MEMORY_SCOPE_AGENT);
            while (__hip_atomic_load(gn_, __ATOMIC_RELAXED, __HIP_MEMORY_SCOPE_AGENT) < target)
                __builtin_amdgcn_s_sleep(2);
        }
    }
    __syncthreads();
}

// =================== persistent word-LSTM scan (SCHUNK steps, both dirs) ==============
// grid 256 = dir(2) x part(128, 4 cells each). h state: packed u32 (hi<<16|lo) in HP,
// exchanged via agent-scope atomics (bypass non-coherent L2). Whh/Ax: plain cached loads.
__global__ __launch_bounds__(256, 1)
void word_scan(const float* __restrict__ AxF, const float* __restrict__ AxB,
               const u16* __restrict__ wrFh, const u16* __restrict__ wrFl,
               const u16* __restrict__ wrBh, const u16* __restrict__ wrBl,
               u32* __restrict__ HP,          // [par][dir][64][512] packed
               float* __restrict__ CW,        // [dir][64*512]
               u16* __restrict__ Eh, u16* __restrict__ El,
               u32* __restrict__ bar, int jc)
{
    const int blk = blockIdx.x;
    const int dir = blk >> 7;
    const int part = blk & 127;
    const int c0  = part * 4;
    const float* Ax = dir ? AxB : AxF;
    const u16* Wh = dir ? wrBh : wrFh;
    const u16* Wl = dir ? wrBl : wrFl;
    u32* fl_ = bar + dir*4096;
    u32* gn_ = bar + 8192 + dir*32;

    __shared__ float zsc[4][16][17];

    const int tid = threadIdx.x;
    const int lane = tid & 63, wv = tid >> 6;
    const int quad = lane >> 4, l15 = lane & 15;

    // B fragments: lane l15 -> gate row; Whh row j = (r>>2)*512 + c0 + (r&3)
    const size_t jrow = (size_t)((l15 >> 2)*HWID + c0 + (l15 & 3)) * HWID;
    bf16x8 bh[16], bl[16];
    #pragma unroll
    for (int kc=0; kc<16; kc++){
        bh[kc] = *(const bf16x8*)&Wh[jrow + kc*32 + quad*8];
        bl[kc] = *(const bf16x8*)&Wl[jrow + kc*32 + quad*8];
    }

    const int batch = wv*16 + l15;
    const int cell  = c0 + quad;
    float creg = CW[dir*(BATCH*HWID) + batch*HWID + cell];
    const size_t abase = (size_t)batch*HWID + quad*8;   // u32 units

    // Ax prefetch for t=0
    float ax0, ax1, ax2, ax3;
    {
        const int lr0 = dir ? (SCHUNK-1) : 0;
        const float* axp = Ax + ((size_t)(lr0*BATCH + batch))*GW + cell;
        ax0 = axp[0]; ax1 = axp[HWID]; ax2 = axp[2*HWID]; ax3 = axp[3*HWID];
    }

    for (int t=0; t<SCHUNK; t++){
        const int ss = jc*SCHUNK + t;
        const int s  = dir ? (S_LEN-1-ss) : ss;
        const int par = t & 1;
        const u32* hp = HP + ((size_t)(par*2 + dir))*(BATCH*HWID);

        f32x4 acc = {0.f,0.f,0.f,0.f};
        #pragma unroll
        for (int kc=0; kc<16; kc++){
            const u64* pq = (const u64*)(hp + abase + kc*32);
            u64 q0 = __hip_atomic_load(pq+0, __ATOMIC_RELAXED, __HIP_MEMORY_SCOPE_AGENT);
            u64 q1 = __hip_atomic_load(pq+1, __ATOMIC_RELAXED, __HIP_MEMORY_SCOPE_AGENT);
            u64 q2 = __hip_atomic_load(pq+2, __ATOMIC_RELAXED, __HIP_MEMORY_SCOPE_AGENT);
            u64 q3 = __hip_atomic_load(pq+3, __ATOMIC_RELAXED, __HIP_MEMORY_SCOPE_AGENT);
            u32 cw[8] = {(u32)q0, (u32)(q0>>32), (u32)q1, (u32)(q1>>32),
                         (u32)q2, (u32)(q2>>32), (u32)q3, (u32)(q3>>32)};
            bf16x8 ah, al8;
            #pragma unroll
            for (int j=0;j<8;j++){
                ah[j]  = (short)(cw[j] >> 16);
                al8[j] = (short)(cw[j] & 0xffffu);
            }
            acc = __builtin_amdgcn_mfma_f32_16x16x32_bf16(ah,  bh[kc], acc, 0,0,0);
            acc = __builtin_amdgcn_mfma_f32_16x16x32_bf16(ah,  bl[kc], acc, 0,0,0);
            acc = __builtin_amdgcn_mfma_f32_16x16x32_bf16(al8, bh[kc], acc, 0,0,0);
        }
        // z roundtrip (per-wave LDS region; in-order DS pipe within wave)
        #pragma unroll
        for (int i=0;i<4;i++) zsc[wv][quad*4+i][l15] = acc[i];
        float zi = zsc[wv][l15][quad]     + ax0;
        float zf = zsc[wv][l15][4+quad]   + ax1;
        float zg = zsc[wv][l15][8+quad]   + ax2;
        float zo = zsc[wv][l15][12+quad]  + ax3;
        float cn = sigf(zf)*creg + sigf(zi)*tanhf(zg);
        creg = cn;
        float hv = sigf(zo)*tanhf(cn);
        u16 h_, l_; split2(hv, h_, l_);
        u32 packed = ((u32)h_ << 16) | (u32)l_;
        u32* np = HP + ((size_t)((1-par)*2 + dir))*(BATCH*HWID);
        __hip_atomic_store(&np[batch*HWID + cell], packed, __ATOMIC_RELAXED, __HIP_MEMORY_SCOPE_AGENT);
        size_t ei = ((size_t)(s*BATCH + batch))*(2*HWID) + dir*HWID + cell;
        Eh[ei] = h_; El[ei] = l_;

        if (t < SCHUNK-1){
            // prefetch Ax for t+1 (static data; overlaps barrier wait)
            const int lr = dir ? (SCHUNK-2-t) : (t+1);
            const float* axp = Ax + ((size_t)(lr*BATCH + batch))*GW + cell;
            ax0 = axp[0]; ax1 = axp[HWID]; ax2 = axp[2*HWID]; ax3 = axp[3*HWID];
            gridbar2(fl_, gn_, part, (u32)(ss + 1));
        }
    }
    CW[dir*(BATCH*HWID) + batch*HWID + cell] = creg;
}

// ---------------- CRF log-likelihood (one wave per batch) ------------------------------
__global__ __launch_bounds__(64)
void crf_loss(const float* __restrict__ logits, const int* __restrict__ tags,
              const float* __restrict__ trans, const float* __restrict__ start,
              const float* __restrict__ endt, float* __restrict__ out)
{
    int b = blockIdx.x, lane = threadIdx.x;
    __shared__ float trs[TT*TT];
    __shared__ float as_[TT];
    __shared__ float red[64];
    for (int i=lane;i<TT*TT;i+=64) trs[i]=trans[i];
    __syncthreads();
    float alpha = (lane<TT) ? (start[lane] + logits[b*TT + lane]) : -1e30f;
    for (int s=1;s<S_LEN;s++){
        if (lane<TT) as_[lane]=alpha;
        __syncthreads();
        if (lane<TT){
            float m = -1e30f;
            for (int f=0;f<TT;f++){ float v=as_[f]+trs[f*TT+lane]; m = fmaxf(m,v); }
            float sm = 0.f;
            for (int f=0;f<TT;f++){ float v=as_[f]+trs[f*TT+lane]; sm += __expf(v-m); }
            alpha = m + __logf(sm) + logits[((size_t)s*BATCH+b)*TT + lane];
        }
        __syncthreads();
    }
    if (lane<TT) red[lane] = alpha + endt[lane];
    __syncthreads();
    float logZ = 0.f;
    if (lane==0){
        float m=-1e30f; for(int i=0;i<TT;i++) m=fmaxf(m,red[i]);
        float sm=0.f;   for(int i=0;i<TT;i++) sm += __expf(red[i]-m);
        logZ = m + __logf(sm);
    }
    __syncthreads();
    float sc = 0.f;
    for (int s=lane;s<S_LEN;s+=64){
        int tg = tags[s*BATCH+b];
        sc += logits[((size_t)s*BATCH+b)*TT + tg];
        if (s+1 < S_LEN){ int t2 = tags[(s+1)*BATCH+b]; sc += trs[tg*TT+t2]; }
    }
    red[lane]=sc; __syncthreads();
    if (lane==0){
        float tot = 0.f; for (int i=0;i<64;i++) tot += red[i];
        tot += start[tags[b]] + endt[tags[(S_LEN-1)*BATCH + b]];
        atomicAdd(out, -(tot - logZ));
    }
}

// ---------------- Viterbi (one wave per batch) -----------------------------------------
__global__ __launch_bounds__(64)
void viterbi_k(const float* __restrict__ logits, const float* __restrict__ trans,
               const float* __restrict__ start, const float* __restrict__ endt,
               int* __restrict__ bp, float* __restrict__ outTags)
{
    int b = blockIdx.x, lane = threadIdx.x;
    __shared__ float trs[TT*TT];
    __shared__ float vs_[TT];
    for (int i=lane;i<TT*TT;i+=64) trs[i]=trans[i];
    __syncthreads();
    float v = (lane<TT) ? (start[lane] + logits[b*TT+lane]) : -1e30f;
    for (int s=1;s<S_LEN;s++){
        if (lane<TT) vs_[lane]=v;
        __syncthreads();
        if (lane<TT){
            float best=-1e30f; int bj=0;
            for (int f=0;f<TT;f++){
                float val = vs_[f]+trs[f*TT+lane];
                if (val > best){ best=val; bj=f; }
            }
            v = best + logits[((size_t)s*BATCH+b)*TT+lane];
            bp[((size_t)(s-1)*BATCH+b)*TT + lane] = bj;
        }
        __syncthreads();
    }
    if (lane<TT) vs_[lane] = v + endt[lane];
    __syncthreads();
    if (lane==0){
        float best=-1e30f; int last=0;
        for (int i=0;i<TT;i++){ if (vs_[i] > best){best=vs_[i]; last=i;} }
        int tag=last;
        outTags[b*S_LEN + (S_LEN-1)] = (float)tag;
        for (int s=S_LEN-2;s>=0;s--){
            tag = bp[((size_t)s*BATCH+b)*TT + tag];
            outTags[b*S_LEN + s] = (float)tag;
        }
    }
}

// ======================================================================================
extern "C" void kernel_launch(void* const* d_in, const int* in_sizes, int n_in,
                              void* d_out, int out_size, void* d_ws, size_t ws_size,
                              hipStream_t stream)
{
    const int* word_in = (const int*)d_in[0];
    const int* char_in = (const int*)d_in[1];
    const int* cap_in  = (const int*)d_in[2];
    const int* tag_in  = (const int*)d_in[3];
    const float* wemb  = (const float*)d_in[4];
    const float* cemb  = (const float*)d_in[5];
    const float* chemb = (const float*)d_in[6];
    const float* cWihF=(const float*)d_in[7],  *cWhhF=(const float*)d_in[8];
    const float* cBihF=(const float*)d_in[9],  *cBhhF=(const float*)d_in[10];
    const float* cWihB=(const float*)d_in[11], *cWhhB=(const float*)d_in[12];
    const float* cBihB=(const float*)d_in[13], *cBhhB=(const float*)d_in[14];
    const float* wWihF=(const float*)d_in[15], *wWhhF=(const float*)d_in[16];
    const float* wBihF=(const float*)d_in[17], *wBhhF=(const float*)d_in[18];
    const float* wWihB=(const float*)d_in[19], *wWhhB=(const float*)d_in[20];
    const float* wBihB=(const float*)d_in[21], *wBhhB=(const float*)d_in[22];
    const float* ff1W=(const float*)d_in[23],  *ff1b=(const float*)d_in[24];
    const float* ff2W=(const float*)d_in[25],  *ff2b=(const float*)d_in[26];
    const float* trans=(const float*)d_in[27];
    const float* startT=(const float*)d_in[28], *endT=(const float*)d_in[29];
    float* out = (float*)d_out;

    // ---- workspace layout (fl units), ~143 MB ------------------------------
    float* W = (float*)d_ws;
    size_t o = 0;
    float* XhF  = W + o; o += (size_t)NSB*DDP/2;      // X hi pairs (u16)
    float* XlF  = W + o; o += (size_t)NSB*DDP/2;
    float* AXCF = W + o; o += (size_t)CROWS*GW;       // 2.1M fl
    float* AXCB = W + o; o += (size_t)CROWS*GW;
    float* EhF  = W + o; o += (size_t)NSB*1024/2;     // ENC hi pairs
    float* ElF  = W + o; o += (size_t)NSB*1024/2;
    float* PF   = W + o; o += 128*GC;
    float* PB   = W + o; o += 128*GC;
    float* BSF  = W + o; o += GW;
    float* BSB  = W + o; o += GW;
    float* CWb  = W + o; o += (size_t)2*BATCH*HWID;   // word c state
    float* WFh  = W + o; o += (size_t)GW*DDP/2;       // word Wih pairs
    float* WFl  = W + o; o += (size_t)GW*DDP/2;
    float* WBh  = W + o; o += (size_t)GW*DDP/2;
    float* WBl  = W + o; o += (size_t)GW*DDP/2;
    float* cFh  = W + o; o += (size_t)GC*HC/2;        // char Whh pairs
    float* cFl  = W + o; o += (size_t)GC*HC/2;
    float* cBh  = W + o; o += (size_t)GC*HC/2;
    float* cBl  = W + o; o += (size_t)GC*HC/2;
    float* f1h  = W + o; o += (size_t)HWID*1024/2;    // ff1W pairs
    float* f1l  = W + o; o += (size_t)HWID*1024/2;
    float* wrFhF= W + o; o += (size_t)GW*HWID/2;      // word Whh pairs
    float* wrFlF= W + o; o += (size_t)GW*HWID/2;
    float* wrBhF= W + o; o += (size_t)GW*HWID/2;
    float* wrBlF= W + o; o += (size_t)GW*HWID/2;
    float* HPF  = W + o; o += (size_t)2*2*BATCH*HWID; // packed h u32 [par][dir][64][512]
    float* barF = W + o; o += 8256;                   // flags[2][4096] + gen[2][32]

    u16* Xh = (u16*)XhF;  u16* Xl = (u16*)XlF;
    u16* Eh = (u16*)EhF;  u16* El = (u16*)ElF;
    // char state aliases inside ENC region (disjoint in time)
    u16*   Hh = (u16*)EhF;
    u16*   Hl = (u16*)(EhF + (size_t)NSEQ*HC);
    float* Cc = EhF + (size_t)2*NSEQ*HC;
    float* HFF = AXCF;                  // ff1 hidden (spans AXCF+AXCB)
    float* LOG = XhF;                   // logits, after X dead
    int*   BP  = (int*)(XhF + (size_t)NSB*TT);
    u32* HP  = (u32*)HPF;
    u32* bar = (u32*)barF;

    dim3 blk(256);

    // ---- precomputes -------------------------------------------------------
    char_pmat<<<(2*128*GC+255)/256, blk, 0, stream>>>(chemb, cWihF, cWihB,
                                                      cBihF, cBhhF, cBihB, cBhhB, PF, PB);
    x_fill_pair<<<((size_t)NSB*320+255)/256, blk, 0, stream>>>(word_in, cap_in, wemb, cemb, Xh, Xl);
    bias_sum<<<(GW+255)/256, blk, 0, stream>>>(wBihF, wBhhF, wBihB, wBhhB, BSF, BSB, GW);
    pad_w_split<<<(2*GW*DDP+255)/256, blk, 0, stream>>>(wWihF, wWihB,
                                                        (u16*)WFh,(u16*)WFl,(u16*)WBh,(u16*)WBl);
    split_pair<<<(GC*HC+255)/256, blk, 0, stream>>>(cWhhF, (u16*)cFh, (u16*)cFl, GC*HC);
    split_pair<<<(GC*HC+255)/256, blk, 0, stream>>>(cWhhB, (u16*)cBh, (u16*)cBl, GC*HC);
    split_pair<<<(HWID*1024+255)/256, blk, 0, stream>>>(ff1W, (u16*)f1h, (u16*)f1l, HWID*1024);
    split_pair<<<(GW*HWID+255)/256, blk, 0, stream>>>(wWhhF, (u16*)wrFhF, (u16*)wrFlF, GW*HWID);
    split_pair<<<(GW*HWID+255)/256, blk, 0, stream>>>(wWhhB, (u16*)wrBhF, (u16*)wrBlF, GW*HWID);

    // ---- char BiLSTM (MFMA) ------------------------------------------------
    zero_f<<<((size_t)NSB*1024/2+255)/256, blk, 0, stream>>>(EhF, NSB*1024/2); // h/c init
    for (int k=0;k<WLEN;k++){
        char_step_mfma<<<1024, blk, 0, stream>>>((u16*)cFh,(u16*)cFl,(u16*)cBh,(u16*)cBl,
                                                 PF, PB, char_in, Hh, Hl, Cc, Xh, Xl, k);
    }

    // ---- word BiLSTM: chunked Ax GEMM + persistent scan --------------------
    zero_f<<<(2*BATCH*HWID+255)/256, blk, 0, stream>>>(CWb, 2*BATCH*HWID);
    zero_f<<<(2*2*BATCH*HWID+255)/256, blk, 0, stream>>>(HPF, 2*2*BATCH*HWID);
    zero_f<<<(8256+255)/256, blk, 0, stream>>>(barF, 8256);
    dim3 gax(CROWS/128, GW/128);   // (8, 16)
    for (int j=0;j<S_LEN/SCHUNK;j++){
        int sbf = j*SCHUNK;
        int sbb = (S_LEN-SCHUNK) - j*SCHUNK;
        gemm_mfma<<<gax, blk, 0, stream>>>(Xh + (size_t)sbf*BATCH*DDP, Xl + (size_t)sbf*BATCH*DDP, DDP,
                                           (u16*)WFh, (u16*)WFl, DDP,
                                           AXCF, GW, DDP, BSF, 0);
        gemm_mfma<<<gax, blk, 0, stream>>>(Xh + (size_t)sbb*BATCH*DDP, Xl + (size_t)sbb*BATCH*DDP, DDP,
                                           (u16*)WBh, (u16*)WBl, DDP,
                                           AXCB, GW, DDP, BSB, 0);
        word_scan<<<256, blk, 0, stream>>>(AXCF, AXCB,
                                           (u16*)wrFhF, (u16*)wrFlF, (u16*)wrBhF, (u16*)wrBlF,
                                           HP, CWb, Eh, El, bar, j);
    }

    // ---- feed-forward head -------------------------------------------------
    dim3 g1(NSB/128, HWID/128);    // (128, 4)
    gemm_mfma<<<g1, blk, 0, stream>>>(Eh, El, 1024, (u16*)f1h, (u16*)f1l, 1024,
                                      HFF, HWID, 1024, ff1b, 1);
    dim3 g2(NSB/128, 1);
    gemm128<<<g2, blk, 0, stream>>>(HFF, HWID, ff2W, HWID, LOG, TT,
                                    NSB, TT, HWID, ff2b, 0);

    // ---- CRF loss + Viterbi ------------------------------------------------
    zero_f<<<1, dim3(64), 0, stream>>>(out, 1);
    crf_loss<<<BATCH, dim3(64), 0, stream>>>(LOG, tag_in, trans, startT, endT, out);
    viterbi_k<<<BATCH, dim3(64), 0, stream>>>(LOG, trans, startT, endT, BP, out+1);
}